// Round 1
// baseline (224.373 us; speedup 1.0000x reference)
//
#include <hip/hip_runtime.h>
#include <hip/hip_bf16.h>
#include <float.h>

#define N_NODES 5000
#define F_IN    128
#define HC      128
#define GH      256
#define NE      320000
#define NET     325000   // NE + N self loops
#define MPAD    5120

typedef __bf16 bf16;
typedef __attribute__((ext_vector_type(8))) __bf16 bf16x8;
typedef __attribute__((ext_vector_type(4))) float  f32x4;

__device__ __forceinline__ float lrelu(float v) { return v > 0.f ? v : 0.2f * v; }

// ---------------- counting-sort init: cnt[i] = 1 (self loop) ----------------
__global__ void k_init_cnt(int* __restrict__ cnt) {
  int i = blockIdx.x * 256 + threadIdx.x;
  if (i < N_NODES) cnt[i] = 1;
}

// ---------------- xl = x@W_l + b_l ; xr = x@W_r + b_r ----------------
__global__ __launch_bounds__(256) void k_lin(
    const float* __restrict__ x,
    const float* __restrict__ Wl, const float* __restrict__ bl,
    const float* __restrict__ Wr, const float* __restrict__ br,
    float* __restrict__ xl, float* __restrict__ xr) {
  __shared__ float xs[F_IN];
  int node = blockIdx.x, t = threadIdx.x;
  if (t < F_IN) xs[t] = x[node * F_IN + t];
  __syncthreads();
  int col = t & 127;
  const float* W = (t < 128) ? Wl : Wr;
  float acc = (t < 128) ? bl[col] : br[col];
#pragma unroll 16
  for (int k = 0; k < F_IN; ++k) acc = fmaf(xs[k], W[k * HC + col], acc);
  float* out = (t < 128) ? xl : xr;
  out[node * HC + col] = acc;
}

// ---------------- decode edge_index (int32 or int64) + histogram ----------------
__global__ void k_decode_hist(const int* __restrict__ ei, int* __restrict__ src32,
                              int* __restrict__ dst32, int* __restrict__ cnt) {
  __shared__ int mode;  // 1 => data is int64 little-endian
  if (threadIdx.x == 0) {
    int f = 0;
    for (int q = 1; q < 128; q += 2) f |= ei[q];
    mode = (f == 0) ? 1 : 0;
  }
  __syncthreads();
  int e = blockIdx.x * 256 + threadIdx.x;
  if (e >= NE) return;
  int s, d;
  if (mode) { s = ei[2 * e]; d = ei[2 * (NE + e)]; }
  else      { s = ei[e];     d = ei[NE + e]; }
  src32[e] = s; dst32[e] = d;
  atomicAdd(&cnt[d], 1);
}

// ---------------- exclusive scan of cnt -> offs[N+1], cursor ----------------
__global__ __launch_bounds__(1024) void k_scan(const int* __restrict__ cnt,
    int* __restrict__ offs, int* __restrict__ cursor) {
  __shared__ int part[1024];
  int t = threadIdx.x;
  int base = t * 5;
  int v[5]; int s = 0;
#pragma unroll
  for (int i = 0; i < 5; ++i) {
    int idx = base + i;
    v[i] = (idx < N_NODES) ? cnt[idx] : 0;
    s += v[i];
  }
  part[t] = s;
  __syncthreads();
  for (int off = 1; off < 1024; off <<= 1) {
    int add = (t >= off) ? part[t - off] : 0;
    __syncthreads();
    part[t] += add;
    __syncthreads();
  }
  int run = (t == 0) ? 0 : part[t - 1];
#pragma unroll
  for (int i = 0; i < 5; ++i) {
    int idx = base + i;
    if (idx < N_NODES) { offs[idx] = run; cursor[idx] = run; run += v[i]; }
    else if (idx == N_NODES) { offs[idx] = run; }
  }
}

// ---------------- scatter edges into CSR by destination ----------------
__global__ void k_scatter(const int* __restrict__ src32, const int* __restrict__ dst32,
                          int* __restrict__ cursor, int* __restrict__ csr) {
  int p = blockIdx.x * 256 + threadIdx.x;
  if (p >= NET) return;
  int s, d;
  if (p < NE) { s = src32[p]; d = dst32[p]; }
  else        { s = d = p - NE; }
  int pos = atomicAdd(&cursor[d], 1);
  csr[pos] = s;
}

// ---------------- GATv2: one wave per node, online softmax ----------------
__global__ __launch_bounds__(256) void k_gat(
    const float* __restrict__ xl, const float* __restrict__ xr,
    const int* __restrict__ csr, const int* __restrict__ offs,
    const float* __restrict__ att, const float* __restrict__ gbias,
    bf16* __restrict__ gat_b) {
  int lane = threadIdx.x & 63;
  int node = blockIdx.x * 4 + (threadIdx.x >> 6);
  int f1 = lane, f2 = lane + 64;
  float xr1 = xr[node * HC + f1], xr2 = xr[node * HC + f2];
  float at1 = att[f1], at2 = att[f2];
  float m1 = -FLT_MAX, m2 = -FLT_MAX;
  float d1 = 0.f, d2 = 0.f, a1 = 0.f, a2 = 0.f;
  int beg = offs[node], end = offs[node + 1];
  for (int p = beg; p < end; ++p) {
    int j = csr[p];
    float v1 = xl[j * HC + f1], v2 = xl[j * HC + f2];
    float t1 = lrelu(v1 + xr1) * at1;
    float t2 = lrelu(v2 + xr2) * at2;
#pragma unroll
    for (int s = 1; s < 32; s <<= 1) { t1 += __shfl_xor(t1, s); t2 += __shfl_xor(t2, s); }
    // t1 = e for head (lane>>5) in {0,1}; t2 = e for head 2+(lane>>5)
    float mn1 = fmaxf(m1, t1);
    float sc1 = __expf(m1 - mn1);
    float p1  = __expf(t1 - mn1);
    d1 = d1 * sc1 + p1; a1 = a1 * sc1 + p1 * v1; m1 = mn1;
    float mn2 = fmaxf(m2, t2);
    float sc2 = __expf(m2 - mn2);
    float p2  = __expf(t2 - mn2);
    d2 = d2 * sc2 + p2; a2 = a2 * sc2 + p2 * v2; m2 = mn2;
  }
  gat_b[node * HC + f1] = (bf16)(a1 / d1 + gbias[f1]);
  gat_b[node * HC + f2] = (bf16)(a2 / d2 + gbias[f2]);
}

// ---------------- f32 -> bf16 conversion ----------------
__global__ void k_f32_to_bf16(const float* __restrict__ in, bf16* __restrict__ out, int n) {
  int i = blockIdx.x * 256 + threadIdx.x;
  if (i < n) out[i] = (bf16)in[i];
}

// ---------------- bf16 MFMA GEMM, C = A @ B^T + bias (A[M][K], B[N][K]) ----------------
__global__ __launch_bounds__(256) void gemm_nt_bf16(
    const bf16* __restrict__ A, const bf16* __restrict__ B,
    const float* __restrict__ bias, float* __restrict__ Cout,
    int K, int ldc, int Mstore, int Nstore) {
  __shared__ bf16 Al[128][32];
  __shared__ bf16 Bl[128][32];
  int t = threadIdx.x;
  int lane = t & 63, wave = t >> 6;
  int wm = wave >> 1, wn = wave & 1;
  int bm0 = blockIdx.x * 128;
  int bn0 = blockIdx.y * 128;
  int r16 = lane & 15, kg = lane >> 4;
  f32x4 acc[4][4] = {};

  for (int k0 = 0; k0 < K; k0 += 32) {
#pragma unroll
    for (int p = 0; p < 2; ++p) {
      int idx = p * 256 + t;                 // 0..511 -> 128 rows x 4 chunks
      int row = idx >> 2, kc = (idx & 3) * 8;
      *reinterpret_cast<int4*>(&Al[row][kc]) =
          *reinterpret_cast<const int4*>(&A[(size_t)(bm0 + row) * K + k0 + kc]);
      *reinterpret_cast<int4*>(&Bl[row][kc]) =
          *reinterpret_cast<const int4*>(&B[(size_t)(bn0 + row) * K + k0 + kc]);
    }
    __syncthreads();
    bf16x8 af[4], bfr[4];
#pragma unroll
    for (int m = 0; m < 4; ++m)
      af[m] = *reinterpret_cast<const bf16x8*>(&Al[wm * 64 + m * 16 + r16][kg * 8]);
#pragma unroll
    for (int n = 0; n < 4; ++n)
      bfr[n] = *reinterpret_cast<const bf16x8*>(&Bl[wn * 64 + n * 16 + r16][kg * 8]);
#pragma unroll
    for (int m = 0; m < 4; ++m)
#pragma unroll
      for (int n = 0; n < 4; ++n)
        acc[m][n] = __builtin_amdgcn_mfma_f32_16x16x32_bf16(af[m], bfr[n], acc[m][n], 0, 0, 0);
    __syncthreads();
  }

#pragma unroll
  for (int m = 0; m < 4; ++m) {
    int grow_base = bm0 + wm * 64 + m * 16 + kg * 4;
#pragma unroll
    for (int n = 0; n < 4; ++n) {
      int gcol = bn0 + wn * 64 + n * 16 + r16;
      if (gcol < Nstore) {
        float bv = bias[gcol];
#pragma unroll
        for (int r = 0; r < 4; ++r) {
          int grow = grow_base + r;
          if (grow < Mstore)
            Cout[(size_t)grow * ldc + gcol] = acc[m][n][r] + bv;
        }
      }
    }
  }
}

// ---------------- GRU gates (h0 = 0) -> h as bf16 ----------------
__global__ __launch_bounds__(256) void k_gru(const float* __restrict__ gi,
    const float* __restrict__ bhh, bf16* __restrict__ hb) {
  int i = blockIdx.x, g = threadIdx.x;
  float gr = gi[i * 768 + g]       + bhh[g];
  float gz = gi[i * 768 + 256 + g] + bhh[256 + g];
  float gn = gi[i * 768 + 512 + g];
  float r = 1.f / (1.f + expf(-gr));
  float z = 1.f / (1.f + expf(-gz));
  float n = tanhf(gn + r * bhh[512 + g]);
  hb[i * GH + g] = (bf16)((1.f - z) * n);
}

// ---------------- std = exp(clip(log_std, -10, 2)) ----------------
__global__ void k_std(const float* __restrict__ ls, float* __restrict__ out) {
  int i = blockIdx.x * 256 + threadIdx.x;
  if (i < N_NODES) out[i] = expf(fminf(fmaxf(ls[i], -10.f), 2.f));
}

extern "C" void kernel_launch(void* const* d_in, const int* in_sizes, int n_in,
                              void* d_out, int out_size, void* d_ws, size_t ws_size,
                              hipStream_t stream) {
  const float* x     = (const float*)d_in[0];
  const int*   ei    = (const int*)d_in[1];
  const float* Wl    = (const float*)d_in[2];
  const float* bl    = (const float*)d_in[3];
  const float* Wr    = (const float*)d_in[4];
  const float* br    = (const float*)d_in[5];
  const float* att   = (const float*)d_in[6];
  const float* gbias = (const float*)d_in[7];
  const float* Wih   = (const float*)d_in[8];
  // d_in[9] = W_hh: unused (h0 = 0)
  const float* bih   = (const float*)d_in[10];
  const float* bhh   = (const float*)d_in[11];
  const float* Wp    = (const float*)d_in[12];
  const float* bp    = (const float*)d_in[13];
  const float* lstd  = (const float*)d_in[14];
  float* out_mean = (float*)d_out;
  float* out_std  = out_mean + (size_t)N_NODES * N_NODES;

  char* w = (char*)d_ws;
  auto carve = [&](size_t bytes) {
    char* p = w; w += (bytes + 255) & ~(size_t)255; return p;
  };
  float* xl    = (float*)carve((size_t)N_NODES * HC * 4);
  float* xr    = (float*)carve((size_t)N_NODES * HC * 4);
  int*   src32 = (int*)carve((size_t)NE * 4);
  int*   dst32 = (int*)carve((size_t)NE * 4);
  int*   cnt   = (int*)carve((size_t)N_NODES * 4);
  int*   offs  = (int*)carve((size_t)(N_NODES + 1) * 4);
  int*   curs  = (int*)carve((size_t)N_NODES * 4);
  int*   csr   = (int*)carve((size_t)NET * 4);
  bf16*  gatb  = (bf16*)carve((size_t)MPAD * HC * 2);
  bf16*  wihb  = (bf16*)carve((size_t)768 * HC * 2);
  float* gi    = (float*)carve((size_t)N_NODES * 768 * 4);
  bf16*  hb    = (bf16*)carve((size_t)MPAD * GH * 2);
  bf16*  wpb   = (bf16*)carve((size_t)MPAD * GH * 2);

  hipMemsetAsync(gatb, 0, (size_t)MPAD * HC * 2, stream);
  hipMemsetAsync(hb,   0, (size_t)MPAD * GH * 2, stream);
  hipMemsetAsync(wpb,  0, (size_t)MPAD * GH * 2, stream);

  k_init_cnt<<<(N_NODES + 255) / 256, 256, 0, stream>>>(cnt);
  k_lin<<<N_NODES, 256, 0, stream>>>(x, Wl, bl, Wr, br, xl, xr);
  k_decode_hist<<<(NE + 255) / 256, 256, 0, stream>>>(ei, src32, dst32, cnt);
  k_scan<<<1, 1024, 0, stream>>>(cnt, offs, curs);
  k_scatter<<<(NET + 255) / 256, 256, 0, stream>>>(src32, dst32, curs, csr);
  k_gat<<<N_NODES / 4, 256, 0, stream>>>(xl, xr, csr, offs, att, gbias, gatb);
  k_f32_to_bf16<<<(768 * HC + 255) / 256, 256, 0, stream>>>(Wih, wihb, 768 * HC);
  k_f32_to_bf16<<<(N_NODES * GH + 255) / 256, 256, 0, stream>>>(Wp, wpb, N_NODES * GH);
  gemm_nt_bf16<<<dim3(MPAD / 128, 768 / 128), 256, 0, stream>>>(
      gatb, wihb, bih, gi, 128, 768, N_NODES, 768);
  k_gru<<<N_NODES, 256, 0, stream>>>(gi, bhh, hb);
  gemm_nt_bf16<<<dim3(MPAD / 128, MPAD / 128), 256, 0, stream>>>(
      hb, wpb, bp, out_mean, 256, N_NODES, N_NODES, N_NODES);
  k_std<<<(N_NODES + 255) / 256, 256, 0, stream>>>(lstd, out_std);
}

// Round 2
// 207.656 us; speedup vs baseline: 1.0805x; 1.0805x over previous
//
#include <hip/hip_runtime.h>
#include <hip/hip_bf16.h>
#include <float.h>

#define N_NODES 5000
#define F_IN    128
#define HC      128
#define GH      256
#define NE      320000
#define NET     325000   // NE + N self loops
#define MPAD    5120

typedef __bf16 bf16;
typedef __attribute__((ext_vector_type(8))) __bf16 bf16x8;
typedef __attribute__((ext_vector_type(4))) float  f32x4;

__device__ __forceinline__ float lrelu(float v) { return v > 0.f ? v : 0.2f * v; }

__device__ __forceinline__ void gload16(const void* g, void* l) {
  __builtin_amdgcn_global_load_lds((const __attribute__((address_space(1))) void*)g,
                                   (__attribute__((address_space(3))) void*)l, 16, 0, 0);
}

// ---------------- zero cnt ----------------
__global__ void k_init_cnt(int* __restrict__ cnt) {
  int i = blockIdx.x * 256 + threadIdx.x;
  if (i < N_NODES) cnt[i] = 0;
}

// ---------------- xl = x@W_l + b_l ; xr = x@W_r + b_r ; + std output ----------------
__global__ __launch_bounds__(256) void k_lin(
    const float* __restrict__ x,
    const float* __restrict__ Wl, const float* __restrict__ bl,
    const float* __restrict__ Wr, const float* __restrict__ br,
    float* __restrict__ xl, float* __restrict__ xr,
    const float* __restrict__ lstd, float* __restrict__ out_std) {
  __shared__ float xs[8][F_IN];
  int t = threadIdx.x;
  int nb = blockIdx.x * 8;
#pragma unroll
  for (int p = 0; p < 4; ++p) {
    int idx = p * 256 + t;
    int nl = idx >> 7, c = idx & 127;
    int gn = nb + nl;
    xs[nl][c] = (gn < N_NODES) ? x[(size_t)gn * F_IN + c] : 0.f;
  }
  __syncthreads();
  int col = t & 127;
  const float* W = (t < 128) ? Wl : Wr;
  float bias = (t < 128) ? bl[col] : br[col];
  float acc[8];
#pragma unroll
  for (int m = 0; m < 8; ++m) acc[m] = bias;
#pragma unroll 8
  for (int k = 0; k < F_IN; ++k) {
    float w = W[k * HC + col];
#pragma unroll
    for (int m = 0; m < 8; ++m) acc[m] = fmaf(xs[m][k], w, acc[m]);
  }
  float* out = (t < 128) ? xl : xr;
#pragma unroll
  for (int m = 0; m < 8; ++m) {
    int gn = nb + m;
    if (gn < N_NODES) out[(size_t)gn * HC + col] = acc[m];
  }
  if (t < 8) {
    int gn = nb + t;
    if (gn < N_NODES) out_std[gn] = expf(fminf(fmaxf(lstd[gn], -10.f), 2.f));
  }
}

// ---------------- decode edge_index (int32 or int64) + histogram (incl self loops) ----------------
__global__ void k_decode_hist(const int* __restrict__ ei, int* __restrict__ src32,
                              int* __restrict__ dst32, int* __restrict__ cnt) {
  __shared__ int mode;  // 1 => data is int64 little-endian
  if (threadIdx.x == 0) {
    int f = 0;
    for (int q = 1; q < 128; q += 2) f |= ei[q];
    mode = (f == 0) ? 1 : 0;
  }
  __syncthreads();
  int e = blockIdx.x * 256 + threadIdx.x;
  if (e >= NET) return;
  if (e >= NE) { atomicAdd(&cnt[e - NE], 1); return; }
  int s, d;
  if (mode) { s = ei[2 * e]; d = ei[2 * (NE + e)]; }
  else      { s = ei[e];     d = ei[NE + e]; }
  src32[e] = s; dst32[e] = d;
  atomicAdd(&cnt[d], 1);
}

// ---------------- exclusive scan of cnt -> offs[N+1], cursor ----------------
__global__ __launch_bounds__(1024) void k_scan(const int* __restrict__ cnt,
    int* __restrict__ offs, int* __restrict__ cursor) {
  __shared__ int part[1024];
  int t = threadIdx.x;
  int base = t * 5;
  int v[5]; int s = 0;
#pragma unroll
  for (int i = 0; i < 5; ++i) {
    int idx = base + i;
    v[i] = (idx < N_NODES) ? cnt[idx] : 0;
    s += v[i];
  }
  part[t] = s;
  __syncthreads();
  for (int off = 1; off < 1024; off <<= 1) {
    int add = (t >= off) ? part[t - off] : 0;
    __syncthreads();
    part[t] += add;
    __syncthreads();
  }
  int run = (t == 0) ? 0 : part[t - 1];
#pragma unroll
  for (int i = 0; i < 5; ++i) {
    int idx = base + i;
    if (idx < N_NODES) { offs[idx] = run; cursor[idx] = run; run += v[i]; }
    else if (idx == N_NODES) { offs[idx] = run; }
  }
}

// ---------------- scatter edges into CSR (src + dst) ----------------
__global__ void k_scatter(const int* __restrict__ src32, const int* __restrict__ dst32,
                          int* __restrict__ cursor, int* __restrict__ csr_s,
                          int* __restrict__ csr_d) {
  int p = blockIdx.x * 256 + threadIdx.x;
  if (p >= NET) return;
  int s, d;
  if (p < NE) { s = src32[p]; d = dst32[p]; }
  else        { s = d = p - NE; }
  int pos = atomicAdd(&cursor[d], 1);
  csr_s[pos] = s;
  csr_d[pos] = d;
}

// ---------------- edge-parallel attention logits: ex4[pos] = exp(e[pos][h]) ----------------
__global__ __launch_bounds__(256) void k_edge(
    const float* __restrict__ xl, const float* __restrict__ xr,
    const int* __restrict__ csr_s, const int* __restrict__ csr_d,
    const float* __restrict__ att, float4* __restrict__ ex4) {
  int p = blockIdx.x * 256 + threadIdx.x;
  if (p >= NET) return;
  int j = csr_s[p], i = csr_d[p];
  const float4* a4 = (const float4*)(xl + (size_t)j * HC);
  const float4* b4 = (const float4*)(xr + (size_t)i * HC);
  const float4* w4 = (const float4*)att;
  float acc[4] = {0.f, 0.f, 0.f, 0.f};
#pragma unroll
  for (int q = 0; q < 32; ++q) {
    float4 a = a4[q], b = b4[q], w = w4[q];
    int h = q >> 3;
    acc[h] += lrelu(a.x + b.x) * w.x + lrelu(a.y + b.y) * w.y +
              lrelu(a.z + b.z) * w.z + lrelu(a.w + b.w) * w.w;
  }
  float4 o;
  o.x = __expf(acc[0]); o.y = __expf(acc[1]);
  o.z = __expf(acc[2]); o.w = __expf(acc[3]);
  ex4[p] = o;
}

// ---------------- node-parallel aggregation: gat_out = (sum ex*v)/(sum ex) + bias ----------------
__global__ __launch_bounds__(256) void k_agg(
    const float* __restrict__ xl, const int* __restrict__ csr_s,
    const int* __restrict__ offs, const float* __restrict__ ex,
    const float* __restrict__ gbias, bf16* __restrict__ gat_b) {
  int lane = threadIdx.x & 63;
  int node = blockIdx.x * 4 + (threadIdx.x >> 6);
  if (node >= N_NODES) return;
  int f1 = lane, f2 = lane + 64;
  int h1 = f1 >> 5, h2 = 2 + h1;
  float acc1 = 0.f, acc2 = 0.f, den1 = 0.f, den2 = 0.f;
  int beg = offs[node], end = offs[node + 1];
  for (int p = beg; p < end; ++p) {
    int j = csr_s[p];
    float e1 = ex[p * 4 + h1], e2 = ex[p * 4 + h2];
    acc1 = fmaf(e1, xl[(size_t)j * HC + f1], acc1); den1 += e1;
    acc2 = fmaf(e2, xl[(size_t)j * HC + f2], acc2); den2 += e2;
  }
  gat_b[(size_t)node * HC + f1] = (bf16)(acc1 / den1 + gbias[f1]);
  gat_b[(size_t)node * HC + f2] = (bf16)(acc2 / den2 + gbias[f2]);
}

// ---------------- f32 -> bf16 conversion (Wih then Wp, merged) ----------------
#define NWIH (768 * HC)
#define NWP  (N_NODES * GH)
__global__ void k_conv(const float* __restrict__ wih, const float* __restrict__ wp,
                       bf16* __restrict__ wihb, bf16* __restrict__ wpb) {
  int i = blockIdx.x * 256 + threadIdx.x;
  if (i < NWIH) { wihb[i] = (bf16)wih[i]; return; }
  int j = i - NWIH;
  if (j < NWP) wpb[j] = (bf16)wp[j];
}

// ---------------- bf16 MFMA GEMM, C = A @ B^T + bias (A[M][K], B[N][K]) ----------------
__global__ __launch_bounds__(256) void gemm_nt_bf16(
    const bf16* __restrict__ A, const bf16* __restrict__ B,
    const float* __restrict__ bias, float* __restrict__ Cout,
    int K, int ldc, int Mstore, int Nstore) {
  __shared__ bf16 Al[128][32];
  __shared__ bf16 Bl[128][32];
  int t = threadIdx.x;
  int lane = t & 63, wave = t >> 6;
  int wm = wave >> 1, wn = wave & 1;
  int bm0 = blockIdx.x * 128;
  int bn0 = blockIdx.y * 128;
  int r16 = lane & 15, kg = lane >> 4;
  int srow = lane >> 2;           // 0..15
  int kc = (lane & 3) * 8;        // 0,8,16,24
  f32x4 acc[4][4] = {};

  for (int k0 = 0; k0 < K; k0 += 32) {
#pragma unroll
    for (int q = 0; q < 2; ++q) {
      int row = wave * 32 + q * 16 + srow;
      gload16(&A[(size_t)(bm0 + row) * K + k0 + kc], &Al[wave * 32 + q * 16][0]);
      gload16(&B[(size_t)(bn0 + row) * K + k0 + kc], &Bl[wave * 32 + q * 16][0]);
    }
    __syncthreads();
    bf16x8 af[4], bfr[4];
#pragma unroll
    for (int m = 0; m < 4; ++m)
      af[m] = *reinterpret_cast<const bf16x8*>(&Al[wm * 64 + m * 16 + r16][kg * 8]);
#pragma unroll
    for (int n = 0; n < 4; ++n)
      bfr[n] = *reinterpret_cast<const bf16x8*>(&Bl[wn * 64 + n * 16 + r16][kg * 8]);
#pragma unroll
    for (int m = 0; m < 4; ++m)
#pragma unroll
      for (int n = 0; n < 4; ++n)
        acc[m][n] = __builtin_amdgcn_mfma_f32_16x16x32_bf16(af[m], bfr[n], acc[m][n], 0, 0, 0);
    __syncthreads();
  }

#pragma unroll
  for (int m = 0; m < 4; ++m) {
    int grow_base = bm0 + wm * 64 + m * 16 + kg * 4;
#pragma unroll
    for (int n = 0; n < 4; ++n) {
      int gcol = bn0 + wn * 64 + n * 16 + r16;
      if (gcol < Nstore) {
        float bv = bias[gcol];
#pragma unroll
        for (int r = 0; r < 4; ++r) {
          int grow = grow_base + r;
          if (grow < Mstore)
            Cout[(size_t)grow * ldc + gcol] = acc[m][n][r] + bv;
        }
      }
    }
  }
}

// ---------------- GRU gates (h0 = 0) -> h as bf16 ----------------
__global__ __launch_bounds__(256) void k_gru(const float* __restrict__ gi,
    const float* __restrict__ bhh, bf16* __restrict__ hb) {
  int i = blockIdx.x, g = threadIdx.x;
  float gr = gi[(size_t)i * 768 + g]       + bhh[g];
  float gz = gi[(size_t)i * 768 + 256 + g] + bhh[256 + g];
  float gn = gi[(size_t)i * 768 + 512 + g];
  float r = 1.f / (1.f + expf(-gr));
  float z = 1.f / (1.f + expf(-gz));
  float n = tanhf(gn + r * bhh[512 + g]);
  hb[(size_t)i * GH + g] = (bf16)((1.f - z) * n);
}

extern "C" void kernel_launch(void* const* d_in, const int* in_sizes, int n_in,
                              void* d_out, int out_size, void* d_ws, size_t ws_size,
                              hipStream_t stream) {
  const float* x     = (const float*)d_in[0];
  const int*   ei    = (const int*)d_in[1];
  const float* Wl    = (const float*)d_in[2];
  const float* bl    = (const float*)d_in[3];
  const float* Wr    = (const float*)d_in[4];
  const float* br    = (const float*)d_in[5];
  const float* att   = (const float*)d_in[6];
  const float* gbias = (const float*)d_in[7];
  const float* Wih   = (const float*)d_in[8];
  // d_in[9] = W_hh: unused (h0 = 0)
  const float* bih   = (const float*)d_in[10];
  const float* bhh   = (const float*)d_in[11];
  const float* Wp    = (const float*)d_in[12];
  const float* bp    = (const float*)d_in[13];
  const float* lstd  = (const float*)d_in[14];
  float* out_mean = (float*)d_out;
  float* out_std  = out_mean + (size_t)N_NODES * N_NODES;

  char* w = (char*)d_ws;
  auto carve = [&](size_t bytes) {
    char* p = w; w += (bytes + 255) & ~(size_t)255; return p;
  };
  float* xl    = (float*)carve((size_t)N_NODES * HC * 4);
  float* xr    = (float*)carve((size_t)N_NODES * HC * 4);
  int*   src32 = (int*)carve((size_t)NE * 4);
  int*   dst32 = (int*)carve((size_t)NE * 4);
  int*   cnt   = (int*)carve((size_t)N_NODES * 4);
  int*   offs  = (int*)carve((size_t)(N_NODES + 1) * 4);
  int*   curs  = (int*)carve((size_t)N_NODES * 4);
  int*   csr_s = (int*)carve((size_t)NET * 4);
  int*   csr_d = (int*)carve((size_t)NET * 4);
  float* ex4   = (float*)carve((size_t)NET * 4 * 4);
  bf16*  gatb  = (bf16*)carve((size_t)MPAD * HC * 2);
  bf16*  wihb  = (bf16*)carve((size_t)768 * HC * 2);
  float* gi    = (float*)carve((size_t)MPAD * 768 * 4);
  bf16*  hb    = (bf16*)carve((size_t)MPAD * GH * 2);
  bf16*  wpb   = (bf16*)carve((size_t)MPAD * GH * 2);

  k_init_cnt<<<(N_NODES + 255) / 256, 256, 0, stream>>>(cnt);
  k_lin<<<(N_NODES + 7) / 8, 256, 0, stream>>>(x, Wl, bl, Wr, br, xl, xr, lstd, out_std);
  k_decode_hist<<<(NET + 255) / 256, 256, 0, stream>>>(ei, src32, dst32, cnt);
  k_scan<<<1, 1024, 0, stream>>>(cnt, offs, curs);
  k_scatter<<<(NET + 255) / 256, 256, 0, stream>>>(src32, dst32, curs, csr_s, csr_d);
  k_edge<<<(NET + 255) / 256, 256, 0, stream>>>(xl, xr, csr_s, csr_d, att, (float4*)ex4);
  k_agg<<<(N_NODES + 3) / 4, 256, 0, stream>>>(xl, csr_s, offs, ex4, gbias, gatb);
  k_conv<<<(NWIH + NWP + 255) / 256, 256, 0, stream>>>(Wih, Wp, wihb, wpb);
  gemm_nt_bf16<<<dim3(MPAD / 128, 768 / 128), 256, 0, stream>>>(
      gatb, wihb, bih, gi, 128, 768, N_NODES, 768);
  k_gru<<<N_NODES, 256, 0, stream>>>(gi, bhh, hb);
  gemm_nt_bf16<<<dim3(MPAD / 128, MPAD / 128), 256, 0, stream>>>(
      hb, wpb, bp, out_mean, 256, N_NODES, N_NODES, N_NODES);
}

// Round 3
// 182.842 us; speedup vs baseline: 1.2271x; 1.1357x over previous
//
#include <hip/hip_runtime.h>
#include <hip/hip_bf16.h>
#include <float.h>

#define N_NODES 5000
#define F_IN    128
#define HC      128
#define GH      256
#define NE      320000
#define NET     325000   // NE + N self loops
#define MPAD    5120

typedef __bf16 bf16;
typedef __attribute__((ext_vector_type(8))) __bf16 bf16x8;
typedef __attribute__((ext_vector_type(4))) float  f32x4;

__device__ __forceinline__ float lrelu(float v) { return v > 0.f ? v : 0.2f * v; }

__device__ __forceinline__ void gload16(const void* g, void* l) {
  __builtin_amdgcn_global_load_lds((const __attribute__((address_space(1))) void*)g,
                                   (__attribute__((address_space(3))) void*)l, 16, 0, 0);
}

// ---------------- zero cnt + f32->bf16 weight conversions (merged) ----------------
#define NWIH (768 * HC)
#define NWP  (N_NODES * GH)
__global__ void k_init_conv(int* __restrict__ cnt,
                            const float* __restrict__ wih, const float* __restrict__ wp,
                            bf16* __restrict__ wihb, bf16* __restrict__ wpb) {
  int i = blockIdx.x * 256 + threadIdx.x;
  if (i < N_NODES) cnt[i] = 0;
  if (i < NWIH) { wihb[i] = (bf16)wih[i]; }
  int j = i - NWIH;
  if (j >= 0 && j < NWP) wpb[j] = (bf16)wp[j];
}

// ---------------- xl = x@W_l + b_l ; xr = x@W_r + b_r ; + std output ----------------
__global__ __launch_bounds__(256) void k_lin(
    const float* __restrict__ x,
    const float* __restrict__ Wl, const float* __restrict__ bl,
    const float* __restrict__ Wr, const float* __restrict__ br,
    float* __restrict__ xl, float* __restrict__ xr,
    const float* __restrict__ lstd, float* __restrict__ out_std) {
  __shared__ float xs[8][F_IN];
  int t = threadIdx.x;
  int nb = blockIdx.x * 8;
#pragma unroll
  for (int p = 0; p < 4; ++p) {
    int idx = p * 256 + t;
    int nl = idx >> 7, c = idx & 127;
    int gn = nb + nl;
    xs[nl][c] = (gn < N_NODES) ? x[(size_t)gn * F_IN + c] : 0.f;
  }
  __syncthreads();
  int col = t & 127;
  const float* W = (t < 128) ? Wl : Wr;
  float bias = (t < 128) ? bl[col] : br[col];
  float acc[8];
#pragma unroll
  for (int m = 0; m < 8; ++m) acc[m] = bias;
#pragma unroll 8
  for (int k = 0; k < F_IN; ++k) {
    float w = W[k * HC + col];
#pragma unroll
    for (int m = 0; m < 8; ++m) acc[m] = fmaf(xs[m][k], w, acc[m]);
  }
  float* out = (t < 128) ? xl : xr;
#pragma unroll
  for (int m = 0; m < 8; ++m) {
    int gn = nb + m;
    if (gn < N_NODES) out[(size_t)gn * HC + col] = acc[m];
  }
  if (t < 8) {
    int gn = nb + t;
    if (gn < N_NODES) out_std[gn] = expf(fminf(fmaxf(lstd[gn], -10.f), 2.f));
  }
}

// ---------------- decode edge_index (int32 or int64) + histogram (incl self loops) ----------------
__global__ void k_decode_hist(const int* __restrict__ ei, int* __restrict__ src32,
                              int* __restrict__ dst32, int* __restrict__ cnt) {
  __shared__ int mode;  // 1 => data is int64 little-endian
  if (threadIdx.x == 0) {
    int f = 0;
    for (int q = 1; q < 128; q += 2) f |= ei[q];
    mode = (f == 0) ? 1 : 0;
  }
  __syncthreads();
  int e = blockIdx.x * 256 + threadIdx.x;
  if (e >= NET) return;
  if (e >= NE) { atomicAdd(&cnt[e - NE], 1); return; }
  int s, d;
  if (mode) { s = ei[2 * e]; d = ei[2 * (NE + e)]; }
  else      { s = ei[e];     d = ei[NE + e]; }
  src32[e] = s; dst32[e] = d;
  atomicAdd(&cnt[d], 1);
}

// ---------------- exclusive scan of cnt -> offs[N+1], cursor ----------------
__global__ __launch_bounds__(1024) void k_scan(const int* __restrict__ cnt,
    int* __restrict__ offs, int* __restrict__ cursor) {
  __shared__ int part[1024];
  int t = threadIdx.x;
  int base = t * 5;
  int v[5]; int s = 0;
#pragma unroll
  for (int i = 0; i < 5; ++i) {
    int idx = base + i;
    v[i] = (idx < N_NODES) ? cnt[idx] : 0;
    s += v[i];
  }
  part[t] = s;
  __syncthreads();
  for (int off = 1; off < 1024; off <<= 1) {
    int add = (t >= off) ? part[t - off] : 0;
    __syncthreads();
    part[t] += add;
    __syncthreads();
  }
  int run = (t == 0) ? 0 : part[t - 1];
#pragma unroll
  for (int i = 0; i < 5; ++i) {
    int idx = base + i;
    if (idx < N_NODES) { offs[idx] = run; cursor[idx] = run; run += v[i]; }
    else if (idx == N_NODES) { offs[idx] = run; }
  }
}

// ---------------- scatter edges into CSR (src + dst) ----------------
__global__ void k_scatter(const int* __restrict__ src32, const int* __restrict__ dst32,
                          int* __restrict__ cursor, int* __restrict__ csr_s,
                          int* __restrict__ csr_d) {
  int p = blockIdx.x * 256 + threadIdx.x;
  if (p >= NET) return;
  int s, d;
  if (p < NE) { s = src32[p]; d = dst32[p]; }
  else        { s = d = p - NE; }
  int pos = atomicAdd(&cursor[d], 1);
  csr_s[pos] = s;
  csr_d[pos] = d;
}

// ---------------- edge-parallel attention logits: ex4[pos] = exp(e[pos][h]) ----------------
__global__ __launch_bounds__(256) void k_edge(
    const float* __restrict__ xl, const float* __restrict__ xr,
    const int* __restrict__ csr_s, const int* __restrict__ csr_d,
    const float* __restrict__ att, float4* __restrict__ ex4) {
  int p = blockIdx.x * 256 + threadIdx.x;
  if (p >= NET) return;
  int j = csr_s[p], i = csr_d[p];
  const float4* a4 = (const float4*)(xl + (size_t)j * HC);
  const float4* b4 = (const float4*)(xr + (size_t)i * HC);
  const float4* w4 = (const float4*)att;
  float acc[4] = {0.f, 0.f, 0.f, 0.f};
#pragma unroll
  for (int q = 0; q < 32; ++q) {
    float4 a = a4[q], b = b4[q], w = w4[q];
    int h = q >> 3;
    acc[h] += lrelu(a.x + b.x) * w.x + lrelu(a.y + b.y) * w.y +
              lrelu(a.z + b.z) * w.z + lrelu(a.w + b.w) * w.w;
  }
  float4 o;
  o.x = __expf(acc[0]); o.y = __expf(acc[1]);
  o.z = __expf(acc[2]); o.w = __expf(acc[3]);
  ex4[p] = o;
}

// ---------------- node-parallel aggregation: gat_out = (sum ex*v)/(sum ex) + bias ----------------
__global__ __launch_bounds__(256) void k_agg(
    const float* __restrict__ xl, const int* __restrict__ csr_s,
    const int* __restrict__ offs, const float* __restrict__ ex,
    const float* __restrict__ gbias, bf16* __restrict__ gat_b) {
  int lane = threadIdx.x & 63;
  int node = blockIdx.x * 4 + (threadIdx.x >> 6);
  if (node >= N_NODES) return;
  int f1 = lane, f2 = lane + 64;
  int h1 = f1 >> 5, h2 = 2 + h1;
  float acc1 = 0.f, acc2 = 0.f, den1 = 0.f, den2 = 0.f;
  int beg = offs[node], end = offs[node + 1];
  for (int p = beg; p < end; ++p) {
    int j = csr_s[p];
    float e1 = ex[p * 4 + h1], e2 = ex[p * 4 + h2];
    acc1 = fmaf(e1, xl[(size_t)j * HC + f1], acc1); den1 += e1;
    acc2 = fmaf(e2, xl[(size_t)j * HC + f2], acc2); den2 += e2;
  }
  gat_b[(size_t)node * HC + f1] = (bf16)(acc1 / den1 + gbias[f1]);
  gat_b[(size_t)node * HC + f2] = (bf16)(acc2 / den2 + gbias[f2]);
}

// ---------------- bf16 MFMA GEMM, C = A @ B^T + bias (A[M][K], B[N][K]) ----------------
// 128x128 tile, BK=64, double-buffered LDS, 2-phase prefetch pipeline,
// chunk-XOR LDS swizzle (both-sides: pre-swizzled global source + swizzled read),
// LDS-staged float4 epilogue. Requires K % 64 == 0, grid 1-D, nwg % 8 == 0.
__global__ __launch_bounds__(256) void gemm_nt_bf16(
    const bf16* __restrict__ A, const bf16* __restrict__ B,
    const float* __restrict__ bias, float* __restrict__ Cout,
    int K, int ldc, int Mstore, int Nstore, int nbx) {
  __shared__ char smem[65536];  // [A0 16K][B0 16K][A1 16K][B1 16K] -> then float Cs[128][128]
  int t = threadIdx.x;
  int lane = t & 63, wave = t >> 6;
  int wm = wave >> 1, wn = wave & 1;
  int r16 = lane & 15, kg = lane >> 4;

  // XCD-bijective swizzle (nwg % 8 == 0)
  int nwg = gridDim.x;
  int cpx = nwg >> 3;
  int wg  = blockIdx.x;
  int swz = (wg & 7) * cpx + (wg >> 3);
  int bm0 = (swz % nbx) * 128;
  int bn0 = (swz / nbx) * 128;

  int rsub = lane >> 3;      // 0..7
  int cchk = lane & 7;       // 16B chunk within 128B row

  auto STAGE = [&](int buf, int k0) {
    char* Ab = smem + buf * 32768;
    char* Bb = Ab + 16384;
#pragma unroll
    for (int q = 0; q < 4; ++q) {
      int row = (wave * 4 + q) * 8 + rsub;      // 0..127
      int gc = cchk ^ (row & 7);                // pre-swizzled source chunk
      gload16(&A[(size_t)(bm0 + row) * K + k0 + gc * 8], Ab + (wave * 4 + q) * 1024);
      gload16(&B[(size_t)(bn0 + row) * K + k0 + gc * 8], Bb + (wave * 4 + q) * 1024);
    }
  };

  f32x4 acc[4][4] = {};
  int rbA[4], rbB[4];
#pragma unroll
  for (int m = 0; m < 4; ++m) rbA[m] = (wm * 64 + m * 16 + r16) * 128;
#pragma unroll
  for (int n = 0; n < 4; ++n) rbB[n] = (wn * 64 + n * 16 + r16) * 128;
  int sw7 = r16 & 7;

  int nt = K >> 6;
  STAGE(0, 0);
  __syncthreads();
  for (int tt = 0; tt < nt; ++tt) {
    if (tt + 1 < nt) STAGE((tt & 1) ^ 1, (tt + 1) * 64);
    const char* Ab = smem + (tt & 1) * 32768;
    const char* Bb = Ab + 16384;
#pragma unroll
    for (int ks = 0; ks < 2; ++ks) {
      int ch = ((ks * 4 + kg) ^ sw7) * 16;
      bf16x8 af[4], bfr[4];
#pragma unroll
      for (int m = 0; m < 4; ++m)
        af[m] = *reinterpret_cast<const bf16x8*>(Ab + rbA[m] + ch);
#pragma unroll
      for (int n = 0; n < 4; ++n)
        bfr[n] = *reinterpret_cast<const bf16x8*>(Bb + rbB[n] + ch);
#pragma unroll
      for (int m = 0; m < 4; ++m)
#pragma unroll
        for (int n = 0; n < 4; ++n)
          acc[m][n] = __builtin_amdgcn_mfma_f32_16x16x32_bf16(af[m], bfr[n], acc[m][n], 0, 0, 0);
    }
    __syncthreads();
  }

  // epilogue: bias + LDS transpose-stage -> coalesced float4 stores
  float bv[4];
#pragma unroll
  for (int n = 0; n < 4; ++n) {
    int gcol = bn0 + wn * 64 + n * 16 + r16;
    bv[n] = (gcol < Nstore) ? bias[gcol] : 0.f;
  }
  float* Cs = (float*)smem;
#pragma unroll
  for (int m = 0; m < 4; ++m) {
    int rb = wm * 64 + m * 16 + kg * 4;
#pragma unroll
    for (int n = 0; n < 4; ++n) {
      int cb = wn * 64 + n * 16 + r16;
#pragma unroll
      for (int r = 0; r < 4; ++r)
        Cs[(rb + r) * 128 + cb] = acc[m][n][r] + bv[n];
    }
  }
  __syncthreads();
#pragma unroll
  for (int i = 0; i < 16; ++i) {
    int chunk = i * 256 + t;
    int row = chunk >> 5, cc = chunk & 31;
    int grow = bm0 + row, gcol = bn0 + cc * 4;
    if (grow < Mstore && gcol < Nstore)
      *reinterpret_cast<float4*>(&Cout[(size_t)grow * ldc + gcol]) =
          *reinterpret_cast<const float4*>(&Cs[row * 128 + cc * 4]);
  }
}

// ---------------- GRU gates (h0 = 0) -> h as bf16 ----------------
__global__ __launch_bounds__(256) void k_gru(const float* __restrict__ gi,
    const float* __restrict__ bhh, bf16* __restrict__ hb) {
  int i = blockIdx.x, g = threadIdx.x;
  float gr = gi[(size_t)i * 768 + g]       + bhh[g];
  float gz = gi[(size_t)i * 768 + 256 + g] + bhh[256 + g];
  float gn = gi[(size_t)i * 768 + 512 + g];
  float r = 1.f / (1.f + expf(-gr));
  float z = 1.f / (1.f + expf(-gz));
  float n = tanhf(gn + r * bhh[512 + g]);
  hb[(size_t)i * GH + g] = (bf16)((1.f - z) * n);
}

extern "C" void kernel_launch(void* const* d_in, const int* in_sizes, int n_in,
                              void* d_out, int out_size, void* d_ws, size_t ws_size,
                              hipStream_t stream) {
  const float* x     = (const float*)d_in[0];
  const int*   ei    = (const int*)d_in[1];
  const float* Wl    = (const float*)d_in[2];
  const float* bl    = (const float*)d_in[3];
  const float* Wr    = (const float*)d_in[4];
  const float* br    = (const float*)d_in[5];
  const float* att   = (const float*)d_in[6];
  const float* gbias = (const float*)d_in[7];
  const float* Wih   = (const float*)d_in[8];
  // d_in[9] = W_hh: unused (h0 = 0)
  const float* bih   = (const float*)d_in[10];
  const float* bhh   = (const float*)d_in[11];
  const float* Wp    = (const float*)d_in[12];
  const float* bp    = (const float*)d_in[13];
  const float* lstd  = (const float*)d_in[14];
  float* out_mean = (float*)d_out;
  float* out_std  = out_mean + (size_t)N_NODES * N_NODES;

  char* w = (char*)d_ws;
  auto carve = [&](size_t bytes) {
    char* p = w; w += (bytes + 255) & ~(size_t)255; return p;
  };
  float* xl    = (float*)carve((size_t)N_NODES * HC * 4);
  float* xr    = (float*)carve((size_t)N_NODES * HC * 4);
  int*   src32 = (int*)carve((size_t)NE * 4);
  int*   dst32 = (int*)carve((size_t)NE * 4);
  int*   cnt   = (int*)carve((size_t)N_NODES * 4);
  int*   offs  = (int*)carve((size_t)(N_NODES + 1) * 4);
  int*   curs  = (int*)carve((size_t)N_NODES * 4);
  int*   csr_s = (int*)carve((size_t)NET * 4);
  int*   csr_d = (int*)carve((size_t)NET * 4);
  float* ex4   = (float*)carve((size_t)NET * 4 * 4);
  bf16*  gatb  = (bf16*)carve((size_t)MPAD * HC * 2);
  bf16*  wihb  = (bf16*)carve((size_t)768 * HC * 2);
  float* gi    = (float*)carve((size_t)MPAD * 768 * 4);
  bf16*  hb    = (bf16*)carve((size_t)MPAD * GH * 2);
  bf16*  wpb   = (bf16*)carve((size_t)MPAD * GH * 2);

  k_init_conv<<<(NWIH + NWP + 255) / 256, 256, 0, stream>>>(cnt, Wih, Wp, wihb, wpb);
  k_lin<<<(N_NODES + 7) / 8, 256, 0, stream>>>(x, Wl, bl, Wr, br, xl, xr, lstd, out_std);
  k_decode_hist<<<(NET + 255) / 256, 256, 0, stream>>>(ei, src32, dst32, cnt);
  k_scan<<<1, 1024, 0, stream>>>(cnt, offs, curs);
  k_scatter<<<(NET + 255) / 256, 256, 0, stream>>>(src32, dst32, curs, csr_s, csr_d);
  k_edge<<<(NET + 255) / 256, 256, 0, stream>>>(xl, xr, csr_s, csr_d, att, (float4*)ex4);
  k_agg<<<(N_NODES + 3) / 4, 256, 0, stream>>>(xl, csr_s, offs, ex4, gbias, gatb);
  gemm_nt_bf16<<<40 * 6, 256, 0, stream>>>(gatb, wihb, bih, gi, 128, 768, N_NODES, 768, 40);
  k_gru<<<N_NODES, 256, 0, stream>>>(gi, bhh, hb);
  gemm_nt_bf16<<<40 * 40, 256, 0, stream>>>(hb, wpb, bp, out_mean, 256, N_NODES, N_NODES, N_NODES, 40);
}

// Round 4
// 173.968 us; speedup vs baseline: 1.2897x; 1.0510x over previous
//
#include <hip/hip_runtime.h>
#include <hip/hip_bf16.h>
#include <float.h>

#define N_NODES 5000
#define F_IN    128
#define HC      128
#define GH      256
#define NE      320000
#define NET     325000   // NE + N self loops
#define MPAD    5120
#define NTHR    (1270 * 256)   // k_decode_hist total threads

typedef __bf16 bf16;
typedef __attribute__((ext_vector_type(4))) __bf16 bf16x4;
typedef __attribute__((ext_vector_type(8))) __bf16 bf16x8;
typedef __attribute__((ext_vector_type(4))) float  f32x4;

__device__ __forceinline__ float lrelu(float v) { return v > 0.f ? v : 0.2f * v; }

__device__ __forceinline__ void gload16(const void* g, void* l) {
  __builtin_amdgcn_global_load_lds((const __attribute__((address_space(1))) void*)g,
                                   (__attribute__((address_space(3))) void*)l, 16, 0, 0);
}

// ------- xl/xr = x@W + b (bf16 out), zero cnt, std output. 16 nodes/block -------
__global__ __launch_bounds__(256) void k_lin(
    const float* __restrict__ x,
    const float* __restrict__ Wl, const float* __restrict__ bl,
    const float* __restrict__ Wr, const float* __restrict__ br,
    bf16* __restrict__ xlb, bf16* __restrict__ xrb,
    const float* __restrict__ lstd, float* __restrict__ out_std,
    int* __restrict__ cnt) {
  __shared__ float xs[16][F_IN];
  int t = threadIdx.x;
  int nb = blockIdx.x * 16;
  {
    int i = blockIdx.x * 256 + t;
    if (i < N_NODES) cnt[i] = 0;
  }
#pragma unroll
  for (int p = 0; p < 8; ++p) {
    int idx = p * 256 + t;
    int nl = idx >> 7, c = idx & 127;
    int gn = nb + nl;
    xs[nl][c] = (gn < N_NODES) ? x[(size_t)gn * F_IN + c] : 0.f;
  }
  __syncthreads();
  int col = t & 127;
  const float* W = (t < 128) ? Wl : Wr;
  float bias = (t < 128) ? bl[col] : br[col];
  float acc[16];
#pragma unroll
  for (int m = 0; m < 16; ++m) acc[m] = bias;
#pragma unroll 4
  for (int k = 0; k < F_IN; ++k) {
    float w = W[k * HC + col];
#pragma unroll
    for (int m = 0; m < 16; ++m) acc[m] = fmaf(xs[m][k], w, acc[m]);
  }
  bf16* out = (t < 128) ? xlb : xrb;
#pragma unroll
  for (int m = 0; m < 16; ++m) {
    int gn = nb + m;
    if (gn < N_NODES) out[(size_t)gn * HC + col] = (bf16)acc[m];
  }
  if (t < 16) {
    int gn = nb + t;
    if (gn < N_NODES) out_std[gn] = expf(fminf(fmaxf(lstd[gn], -10.f), 2.f));
  }
}

// ------- decode edge_index + histogram + weight bf16 conversions -------
#define NWIH (768 * HC)
#define NWP  (N_NODES * GH)
__global__ void k_decode_hist(const int* __restrict__ ei, int* __restrict__ src32,
                              int* __restrict__ dst32, int* __restrict__ cnt,
                              const float* __restrict__ wih, const float* __restrict__ wp,
                              bf16* __restrict__ wihb, bf16* __restrict__ wpb) {
  __shared__ int mode;  // 1 => data is int64 little-endian
  if (threadIdx.x == 0) {
    int f = 0;
    for (int q = 1; q < 128; q += 2) f |= ei[q];
    mode = (f == 0) ? 1 : 0;
  }
  __syncthreads();
  int e = blockIdx.x * 256 + threadIdx.x;
  // vectorized f32->bf16 conversions (grid-stride, float4 -> bf16x4)
  for (int i = e; i < NWIH / 4; i += NTHR) {
    float4 v = reinterpret_cast<const float4*>(wih)[i];
    bf16x4 o = {(bf16)v.x, (bf16)v.y, (bf16)v.z, (bf16)v.w};
    *reinterpret_cast<bf16x4*>(&wihb[i * 4]) = o;
  }
  for (int i = e; i < NWP / 4; i += NTHR) {
    float4 v = reinterpret_cast<const float4*>(wp)[i];
    bf16x4 o = {(bf16)v.x, (bf16)v.y, (bf16)v.z, (bf16)v.w};
    *reinterpret_cast<bf16x4*>(&wpb[i * 4]) = o;
  }
  if (e >= NET) return;
  if (e >= NE) { atomicAdd(&cnt[e - NE], 1); return; }
  int s, d;
  if (mode) { s = ei[2 * e]; d = ei[2 * (NE + e)]; }
  else      { s = ei[e];     d = ei[NE + e]; }
  src32[e] = s; dst32[e] = d;
  atomicAdd(&cnt[d], 1);
}

// ---------------- exclusive scan of cnt -> offs[N+1], cursor ----------------
__global__ __launch_bounds__(1024) void k_scan(const int* __restrict__ cnt,
    int* __restrict__ offs, int* __restrict__ cursor) {
  __shared__ int part[1024];
  int t = threadIdx.x;
  int base = t * 5;
  int v[5]; int s = 0;
#pragma unroll
  for (int i = 0; i < 5; ++i) {
    int idx = base + i;
    v[i] = (idx < N_NODES) ? cnt[idx] : 0;
    s += v[i];
  }
  part[t] = s;
  __syncthreads();
  for (int off = 1; off < 1024; off <<= 1) {
    int add = (t >= off) ? part[t - off] : 0;
    __syncthreads();
    part[t] += add;
    __syncthreads();
  }
  int run = (t == 0) ? 0 : part[t - 1];
#pragma unroll
  for (int i = 0; i < 5; ++i) {
    int idx = base + i;
    if (idx < N_NODES) { offs[idx] = run; cursor[idx] = run; run += v[i]; }
    else if (idx == N_NODES) { offs[idx] = run; }
  }
}

// ---------------- scatter edges into CSR (src + dst) ----------------
__global__ void k_scatter(const int* __restrict__ src32, const int* __restrict__ dst32,
                          int* __restrict__ cursor, int* __restrict__ csr_s,
                          int* __restrict__ csr_d) {
  int p = blockIdx.x * 256 + threadIdx.x;
  if (p >= NET) return;
  int s, d;
  if (p < NE) { s = src32[p]; d = dst32[p]; }
  else        { s = d = p - NE; }
  int pos = atomicAdd(&cursor[d], 1);
  csr_s[pos] = s;
  csr_d[pos] = d;
}

// ------- edge-parallel attention logits: ex4[pos] = exp(e[pos][h]) (bf16 in) -------
__global__ __launch_bounds__(256) void k_edge(
    const bf16* __restrict__ xlb, const bf16* __restrict__ xrb,
    const int* __restrict__ csr_s, const int* __restrict__ csr_d,
    const float* __restrict__ att, float4* __restrict__ ex4) {
  int p = blockIdx.x * 256 + threadIdx.x;
  if (p >= NET) return;
  int j = csr_s[p], i = csr_d[p];
  const bf16x8* a8 = (const bf16x8*)(xlb + (size_t)j * HC);
  const bf16x8* b8 = (const bf16x8*)(xrb + (size_t)i * HC);
  float acc[4] = {0.f, 0.f, 0.f, 0.f};
#pragma unroll
  for (int q = 0; q < 16; ++q) {
    bf16x8 a = a8[q], b = b8[q];
    int h = q >> 2;
#pragma unroll
    for (int k = 0; k < 8; ++k) {
      float v = lrelu((float)a[k] + (float)b[k]);
      acc[h] = fmaf(v, att[q * 8 + k], acc[h]);
    }
  }
  float4 o;
  o.x = __expf(acc[0]); o.y = __expf(acc[1]);
  o.z = __expf(acc[2]); o.w = __expf(acc[3]);
  ex4[p] = o;
}

// ------- node-parallel aggregation (bf16 gathers): gat = (sum ex*v)/(sum ex)+bias -------
__global__ __launch_bounds__(256) void k_agg(
    const bf16* __restrict__ xlb, const int* __restrict__ csr_s,
    const int* __restrict__ offs, const float* __restrict__ ex,
    const float* __restrict__ gbias, bf16* __restrict__ gat_b) {
  int lane = threadIdx.x & 63;
  int node = blockIdx.x * 4 + (threadIdx.x >> 6);
  if (node >= N_NODES) return;
  int f1 = lane, f2 = lane + 64;
  int h1 = f1 >> 5, h2 = 2 + h1;
  float acc1 = 0.f, acc2 = 0.f, den1 = 0.f, den2 = 0.f;
  int beg = offs[node], end = offs[node + 1];
  for (int p = beg; p < end; ++p) {
    int j = csr_s[p];
    float e1 = ex[p * 4 + h1], e2 = ex[p * 4 + h2];
    acc1 = fmaf(e1, (float)xlb[(size_t)j * HC + f1], acc1); den1 += e1;
    acc2 = fmaf(e2, (float)xlb[(size_t)j * HC + f2], acc2); den2 += e2;
  }
  gat_b[(size_t)node * HC + f1] = (bf16)(acc1 / den1 + gbias[f1]);
  gat_b[(size_t)node * HC + f2] = (bf16)(acc2 / den2 + gbias[f2]);
}

// ---------------- bf16 MFMA GEMM, C = A @ B^T + bias (A[M][K], B[N][K]) ----------------
// 128x128 tile, BK=64, double-buffered LDS, 2-phase prefetch, chunk-XOR swizzle,
// LDS-staged coalesced epilogue. K % 64 == 0, grid 1-D, nwg % 8 == 0.
// BF16OUT: stores bf16, else float (with float4 stores).
template <bool BF16OUT>
__global__ __launch_bounds__(256) void gemm_nt_bf16(
    const bf16* __restrict__ A, const bf16* __restrict__ B,
    const float* __restrict__ bias, void* __restrict__ Cout,
    int K, int ldc, int Mstore, int Nstore, int nbx) {
  __shared__ char smem[65536];
  int t = threadIdx.x;
  int lane = t & 63, wave = t >> 6;
  int wm = wave >> 1, wn = wave & 1;
  int r16 = lane & 15, kg = lane >> 4;

  int nwg = gridDim.x;
  int cpx = nwg >> 3;
  int wg  = blockIdx.x;
  int swz = (wg & 7) * cpx + (wg >> 3);
  int bm0 = (swz % nbx) * 128;
  int bn0 = (swz / nbx) * 128;

  int rsub = lane >> 3;      // 0..7
  int cchk = lane & 7;       // 16B chunk within 128B row

  auto STAGE = [&](int buf, int k0) {
    char* Ab = smem + buf * 32768;
    char* Bb = Ab + 16384;
#pragma unroll
    for (int q = 0; q < 4; ++q) {
      int row = (wave * 4 + q) * 8 + rsub;
      int gc = cchk ^ (row & 7);
      gload16(&A[(size_t)(bm0 + row) * K + k0 + gc * 8], Ab + (wave * 4 + q) * 1024);
      gload16(&B[(size_t)(bn0 + row) * K + k0 + gc * 8], Bb + (wave * 4 + q) * 1024);
    }
  };

  f32x4 acc[4][4] = {};
  int rbA[4], rbB[4];
#pragma unroll
  for (int m = 0; m < 4; ++m) rbA[m] = (wm * 64 + m * 16 + r16) * 128;
#pragma unroll
  for (int n = 0; n < 4; ++n) rbB[n] = (wn * 64 + n * 16 + r16) * 128;
  int sw7 = r16 & 7;

  int nt = K >> 6;
  STAGE(0, 0);
  __syncthreads();
  for (int tt = 0; tt < nt; ++tt) {
    if (tt + 1 < nt) STAGE((tt & 1) ^ 1, (tt + 1) * 64);
    const char* Ab = smem + (tt & 1) * 32768;
    const char* Bb = Ab + 16384;
#pragma unroll
    for (int ks = 0; ks < 2; ++ks) {
      int ch = ((ks * 4 + kg) ^ sw7) * 16;
      bf16x8 af[4], bfr[4];
#pragma unroll
      for (int m = 0; m < 4; ++m)
        af[m] = *reinterpret_cast<const bf16x8*>(Ab + rbA[m] + ch);
#pragma unroll
      for (int n = 0; n < 4; ++n)
        bfr[n] = *reinterpret_cast<const bf16x8*>(Bb + rbB[n] + ch);
#pragma unroll
      for (int m = 0; m < 4; ++m)
#pragma unroll
        for (int n = 0; n < 4; ++n)
          acc[m][n] = __builtin_amdgcn_mfma_f32_16x16x32_bf16(af[m], bfr[n], acc[m][n], 0, 0, 0);
    }
    __syncthreads();
  }

  float bv[4];
#pragma unroll
  for (int n = 0; n < 4; ++n) {
    int gcol = bn0 + wn * 64 + n * 16 + r16;
    bv[n] = (gcol < Nstore) ? bias[gcol] : 0.f;
  }

  if constexpr (BF16OUT) {
    bf16* Cs = (bf16*)smem;
    bf16* Cg = (bf16*)Cout;
#pragma unroll
    for (int m = 0; m < 4; ++m) {
      int rb = wm * 64 + m * 16 + kg * 4;
#pragma unroll
      for (int n = 0; n < 4; ++n) {
        int cb = wn * 64 + n * 16 + r16;
#pragma unroll
        for (int r = 0; r < 4; ++r)
          Cs[(rb + r) * 128 + cb] = (bf16)(acc[m][n][r] + bv[n]);
      }
    }
    __syncthreads();
#pragma unroll
    for (int i = 0; i < 8; ++i) {
      int chunk = i * 256 + t;              // 2048 chunks of 8 bf16
      int row = chunk >> 4, c8 = chunk & 15;
      int grow = bm0 + row, gcol = bn0 + c8 * 8;
      if (grow < Mstore && gcol < Nstore)
        *reinterpret_cast<int4*>(&Cg[(size_t)grow * ldc + gcol]) =
            *reinterpret_cast<const int4*>(&Cs[row * 128 + c8 * 8]);
    }
  } else {
    float* Cs = (float*)smem;
    float* Cg = (float*)Cout;
#pragma unroll
    for (int m = 0; m < 4; ++m) {
      int rb = wm * 64 + m * 16 + kg * 4;
#pragma unroll
      for (int n = 0; n < 4; ++n) {
        int cb = wn * 64 + n * 16 + r16;
#pragma unroll
        for (int r = 0; r < 4; ++r)
          Cs[(rb + r) * 128 + cb] = acc[m][n][r] + bv[n];
      }
    }
    __syncthreads();
#pragma unroll
    for (int i = 0; i < 16; ++i) {
      int chunk = i * 256 + t;
      int row = chunk >> 5, cc = chunk & 31;
      int grow = bm0 + row, gcol = bn0 + cc * 4;
      if (grow < Mstore && gcol < Nstore)
        *reinterpret_cast<float4*>(&Cg[(size_t)grow * ldc + gcol]) =
            *reinterpret_cast<const float4*>(&Cs[row * 128 + cc * 4]);
    }
  }
}

// ---------------- GRU gates (h0 = 0, bf16 gi) -> h as bf16 ----------------
__global__ __launch_bounds__(256) void k_gru(const bf16* __restrict__ gi,
    const float* __restrict__ bhh, bf16* __restrict__ hb) {
  int i = blockIdx.x, g = threadIdx.x;
  float gr = (float)gi[(size_t)i * 768 + g]       + bhh[g];
  float gz = (float)gi[(size_t)i * 768 + 256 + g] + bhh[256 + g];
  float gn = (float)gi[(size_t)i * 768 + 512 + g];
  float r = 1.f / (1.f + expf(-gr));
  float z = 1.f / (1.f + expf(-gz));
  float n = tanhf(gn + r * bhh[512 + g]);
  hb[(size_t)i * GH + g] = (bf16)((1.f - z) * n);
}

extern "C" void kernel_launch(void* const* d_in, const int* in_sizes, int n_in,
                              void* d_out, int out_size, void* d_ws, size_t ws_size,
                              hipStream_t stream) {
  const float* x     = (const float*)d_in[0];
  const int*   ei    = (const int*)d_in[1];
  const float* Wl    = (const float*)d_in[2];
  const float* bl    = (const float*)d_in[3];
  const float* Wr    = (const float*)d_in[4];
  const float* br    = (const float*)d_in[5];
  const float* att   = (const float*)d_in[6];
  const float* gbias = (const float*)d_in[7];
  const float* Wih   = (const float*)d_in[8];
  // d_in[9] = W_hh: unused (h0 = 0)
  const float* bih   = (const float*)d_in[10];
  const float* bhh   = (const float*)d_in[11];
  const float* Wp    = (const float*)d_in[12];
  const float* bp    = (const float*)d_in[13];
  const float* lstd  = (const float*)d_in[14];
  float* out_mean = (float*)d_out;
  float* out_std  = out_mean + (size_t)N_NODES * N_NODES;

  char* w = (char*)d_ws;
  auto carve = [&](size_t bytes) {
    char* p = w; w += (bytes + 255) & ~(size_t)255; return p;
  };
  bf16*  xlb   = (bf16*)carve((size_t)N_NODES * HC * 2);
  bf16*  xrb   = (bf16*)carve((size_t)N_NODES * HC * 2);
  int*   src32 = (int*)carve((size_t)NE * 4);
  int*   dst32 = (int*)carve((size_t)NE * 4);
  int*   cnt   = (int*)carve((size_t)N_NODES * 4);
  int*   offs  = (int*)carve((size_t)(N_NODES + 1) * 4);
  int*   curs  = (int*)carve((size_t)N_NODES * 4);
  int*   csr_s = (int*)carve((size_t)NET * 4);
  int*   csr_d = (int*)carve((size_t)NET * 4);
  float* ex4   = (float*)carve((size_t)NET * 4 * 4);
  bf16*  gatb  = (bf16*)carve((size_t)MPAD * HC * 2);
  bf16*  wihb  = (bf16*)carve((size_t)768 * HC * 2);
  bf16*  gi    = (bf16*)carve((size_t)MPAD * 768 * 2);
  bf16*  hb    = (bf16*)carve((size_t)MPAD * GH * 2);
  bf16*  wpb   = (bf16*)carve((size_t)MPAD * GH * 2);

  k_lin<<<(N_NODES + 15) / 16, 256, 0, stream>>>(x, Wl, bl, Wr, br, xlb, xrb, lstd, out_std, cnt);
  k_decode_hist<<<(NET + 255) / 256, 256, 0, stream>>>(ei, src32, dst32, cnt, Wih, Wp, wihb, wpb);
  k_scan<<<1, 1024, 0, stream>>>(cnt, offs, curs);
  k_scatter<<<(NET + 255) / 256, 256, 0, stream>>>(src32, dst32, curs, csr_s, csr_d);
  k_edge<<<(NET + 255) / 256, 256, 0, stream>>>(xlb, xrb, csr_s, csr_d, att, (float4*)ex4);
  k_agg<<<(N_NODES + 3) / 4, 256, 0, stream>>>(xlb, csr_s, offs, ex4, gbias, gatb);
  gemm_nt_bf16<true><<<40 * 6, 256, 0, stream>>>(gatb, wihb, bih, gi, 128, 768, N_NODES, 768, 40);
  k_gru<<<N_NODES, 256, 0, stream>>>(gi, bhh, hb);
  gemm_nt_bf16<false><<<40 * 40, 256, 0, stream>>>(hb, wpb, bp, out_mean, 256, N_NODES, N_NODES, N_NODES, 40);
}

// Round 6
// 168.978 us; speedup vs baseline: 1.3278x; 1.0295x over previous
//
#include <hip/hip_runtime.h>
#include <hip/hip_bf16.h>
#include <float.h>

#define N_NODES 5000
#define F_IN    128
#define HC      128
#define GH      256
#define NE      320000
#define NET     325000   // NE + N self loops
#define MPAD    5120
#define NTHR    (1270 * 256)   // k_decode_hist total threads

typedef __bf16 bf16;
typedef __attribute__((ext_vector_type(4))) __bf16 bf16x4;
typedef __attribute__((ext_vector_type(8))) __bf16 bf16x8;
typedef __attribute__((ext_vector_type(4))) float  f32x4;

__device__ __forceinline__ float lrelu(float v) { return v > 0.f ? v : 0.2f * v; }

__device__ __forceinline__ void gload16(const void* g, void* l) {
  __builtin_amdgcn_global_load_lds((const __attribute__((address_space(1))) void*)g,
                                   (__attribute__((address_space(3))) void*)l, 16, 0, 0);
}

// ------- xl/xr = x@W + b (bf16 out), zero cnt, std output. 16 nodes/block -------
__global__ __launch_bounds__(256) void k_lin(
    const float* __restrict__ x,
    const float* __restrict__ Wl, const float* __restrict__ bl,
    const float* __restrict__ Wr, const float* __restrict__ br,
    bf16* __restrict__ xlb, bf16* __restrict__ xrb,
    const float* __restrict__ lstd, float* __restrict__ out_std,
    int* __restrict__ cnt) {
  __shared__ float xs[16][F_IN];
  int t = threadIdx.x;
  int nb = blockIdx.x * 16;
  {
    int i = blockIdx.x * 256 + t;
    if (i < N_NODES) cnt[i] = 0;
  }
#pragma unroll
  for (int p = 0; p < 8; ++p) {
    int idx = p * 256 + t;
    int nl = idx >> 7, c = idx & 127;
    int gn = nb + nl;
    xs[nl][c] = (gn < N_NODES) ? x[(size_t)gn * F_IN + c] : 0.f;
  }
  __syncthreads();
  int col = t & 127;
  const float* W = (t < 128) ? Wl : Wr;
  float bias = (t < 128) ? bl[col] : br[col];
  float acc[16];
#pragma unroll
  for (int m = 0; m < 16; ++m) acc[m] = bias;
#pragma unroll 4
  for (int k = 0; k < F_IN; ++k) {
    float w = W[k * HC + col];
#pragma unroll
    for (int m = 0; m < 16; ++m) acc[m] = fmaf(xs[m][k], w, acc[m]);
  }
  bf16* out = (t < 128) ? xlb : xrb;
#pragma unroll
  for (int m = 0; m < 16; ++m) {
    int gn = nb + m;
    if (gn < N_NODES) out[(size_t)gn * HC + col] = (bf16)acc[m];
  }
  if (t < 16) {
    int gn = nb + t;
    if (gn < N_NODES) out_std[gn] = expf(fminf(fmaxf(lstd[gn], -10.f), 2.f));
  }
}

// ------- decode edge_index + histogram + weight bf16 conversions -------
#define NWIH (768 * HC)
#define NWP  (N_NODES * GH)
__global__ void k_decode_hist(const int* __restrict__ ei, int* __restrict__ src32,
                              int* __restrict__ dst32, int* __restrict__ cnt,
                              const float* __restrict__ wih, const float* __restrict__ wp,
                              bf16* __restrict__ wihb, bf16* __restrict__ wpb) {
  __shared__ int mode;  // 1 => data is int64 little-endian
  if (threadIdx.x == 0) {
    int f = 0;
    for (int q = 1; q < 128; q += 2) f |= ei[q];
    mode = (f == 0) ? 1 : 0;
  }
  __syncthreads();
  int e = blockIdx.x * 256 + threadIdx.x;
  for (int i = e; i < NWIH / 4; i += NTHR) {
    float4 v = reinterpret_cast<const float4*>(wih)[i];
    bf16x4 o = {(bf16)v.x, (bf16)v.y, (bf16)v.z, (bf16)v.w};
    *reinterpret_cast<bf16x4*>(&wihb[i * 4]) = o;
  }
  for (int i = e; i < NWP / 4; i += NTHR) {
    float4 v = reinterpret_cast<const float4*>(wp)[i];
    bf16x4 o = {(bf16)v.x, (bf16)v.y, (bf16)v.z, (bf16)v.w};
    *reinterpret_cast<bf16x4*>(&wpb[i * 4]) = o;
  }
  if (e >= NET) return;
  if (e >= NE) { atomicAdd(&cnt[e - NE], 1); return; }
  int s, d;
  if (mode) { s = ei[2 * e]; d = ei[2 * (NE + e)]; }
  else      { s = ei[e];     d = ei[NE + e]; }
  src32[e] = s; dst32[e] = d;
  atomicAdd(&cnt[d], 1);
}

// ---------------- exclusive scan of cnt -> offs[N+1], cursor ----------------
__global__ __launch_bounds__(1024) void k_scan(const int* __restrict__ cnt,
    int* __restrict__ offs, int* __restrict__ cursor) {
  __shared__ int part[1024];
  int t = threadIdx.x;
  int base = t * 5;
  int v[5]; int s = 0;
#pragma unroll
  for (int i = 0; i < 5; ++i) {
    int idx = base + i;
    v[i] = (idx < N_NODES) ? cnt[idx] : 0;
    s += v[i];
  }
  part[t] = s;
  __syncthreads();
  for (int off = 1; off < 1024; off <<= 1) {
    int add = (t >= off) ? part[t - off] : 0;
    __syncthreads();
    part[t] += add;
    __syncthreads();
  }
  int run = (t == 0) ? 0 : part[t - 1];
#pragma unroll
  for (int i = 0; i < 5; ++i) {
    int idx = base + i;
    if (idx < N_NODES) { offs[idx] = run; cursor[idx] = run; run += v[i]; }
    else if (idx == N_NODES) { offs[idx] = run; }
  }
}

// ---------------- scatter edges into CSR (src + dst) ----------------
__global__ void k_scatter(const int* __restrict__ src32, const int* __restrict__ dst32,
                          int* __restrict__ cursor, int* __restrict__ csr_s,
                          int* __restrict__ csr_d) {
  int p = blockIdx.x * 256 + threadIdx.x;
  if (p >= NET) return;
  int s, d;
  if (p < NE) { s = src32[p]; d = dst32[p]; }
  else        { s = d = p - NE; }
  int pos = atomicAdd(&cursor[d], 1);
  csr_s[pos] = s;
  csr_d[pos] = d;
}

// ------- edge-parallel attention logits, 16 lanes per edge (coalesced rows) -------
// ex[p*4+h] = exp(e[p][h]). 4 edges per wave, 16 edges per block.
__global__ __launch_bounds__(256) void k_edge(
    const bf16* __restrict__ xlb, const bf16* __restrict__ xrb,
    const int* __restrict__ csr_s, const int* __restrict__ csr_d,
    const float* __restrict__ att, float* __restrict__ ex) {
  int t = threadIdx.x;
  int lane = t & 63;
  int c8 = lane & 15;                          // 8-channel chunk within row
  int p = (blockIdx.x * 4 + (t >> 6)) * 4 + (lane >> 4);
  if (p >= NET) return;
  int j = csr_s[p], i = csr_d[p];
  bf16x8 a = *reinterpret_cast<const bf16x8*>(xlb + (size_t)j * HC + c8 * 8);
  bf16x8 b = *reinterpret_cast<const bf16x8*>(xrb + (size_t)i * HC + c8 * 8);
  float4 w0 = reinterpret_cast<const float4*>(att)[c8 * 2];
  float4 w1 = reinterpret_cast<const float4*>(att)[c8 * 2 + 1];
  float tacc;
  tacc  = lrelu((float)a[0] + (float)b[0]) * w0.x;
  tacc += lrelu((float)a[1] + (float)b[1]) * w0.y;
  tacc += lrelu((float)a[2] + (float)b[2]) * w0.z;
  tacc += lrelu((float)a[3] + (float)b[3]) * w0.w;
  tacc += lrelu((float)a[4] + (float)b[4]) * w1.x;
  tacc += lrelu((float)a[5] + (float)b[5]) * w1.y;
  tacc += lrelu((float)a[6] + (float)b[6]) * w1.z;
  tacc += lrelu((float)a[7] + (float)b[7]) * w1.w;
  tacc += __shfl_xor(tacc, 1);
  tacc += __shfl_xor(tacc, 2);
  // lanes with (c8 & 3) == 0 hold head (c8>>2) sum; write 4 contiguous floats
  if ((c8 & 3) == 0) ex[(size_t)p * 4 + (c8 >> 2)] = __expf(tacc);
}

// ------- node-parallel aggregation (bf16 gathers): gat = (sum ex*v)/(sum ex)+bias -------
__global__ __launch_bounds__(256) void k_agg(
    const bf16* __restrict__ xlb, const int* __restrict__ csr_s,
    const int* __restrict__ offs, const float* __restrict__ ex,
    const float* __restrict__ gbias, bf16* __restrict__ gat_b) {
  int lane = threadIdx.x & 63;
  int node = blockIdx.x * 4 + (threadIdx.x >> 6);
  if (node >= N_NODES) return;
  int f1 = lane, f2 = lane + 64;
  int h1 = f1 >> 5, h2 = 2 + h1;
  float acc1 = 0.f, acc2 = 0.f, den1 = 0.f, den2 = 0.f;
  int beg = offs[node], end = offs[node + 1];
  int p = beg;
  for (; p + 2 <= end; p += 2) {
    int j0 = csr_s[p], j1 = csr_s[p + 1];
    float e10 = ex[(size_t)p * 4 + h1],       e20 = ex[(size_t)p * 4 + h2];
    float e11 = ex[(size_t)(p + 1) * 4 + h1], e21 = ex[(size_t)(p + 1) * 4 + h2];
    float v10 = (float)xlb[(size_t)j0 * HC + f1], v20 = (float)xlb[(size_t)j0 * HC + f2];
    float v11 = (float)xlb[(size_t)j1 * HC + f1], v21 = (float)xlb[(size_t)j1 * HC + f2];
    acc1 = fmaf(e10, v10, acc1); den1 += e10;
    acc2 = fmaf(e20, v20, acc2); den2 += e20;
    acc1 = fmaf(e11, v11, acc1); den1 += e11;
    acc2 = fmaf(e21, v21, acc2); den2 += e21;
  }
  if (p < end) {
    int j = csr_s[p];
    float e1 = ex[(size_t)p * 4 + h1], e2 = ex[(size_t)p * 4 + h2];
    acc1 = fmaf(e1, (float)xlb[(size_t)j * HC + f1], acc1); den1 += e1;
    acc2 = fmaf(e2, (float)xlb[(size_t)j * HC + f2], acc2); den2 += e2;
  }
  gat_b[(size_t)node * HC + f1] = (bf16)(acc1 / den1 + gbias[f1]);
  gat_b[(size_t)node * HC + f2] = (bf16)(acc2 / den2 + gbias[f2]);
}

// ---------------- bf16 MFMA GEMM, C = A @ B^T + bias (A[M][K], B[N][K]) ----------------
// 128x128 tile, BK=64, double-buffered LDS, 2-phase prefetch, chunk-XOR swizzle,
// LDS-staged coalesced epilogue (nontemporal for f32 out). K%64==0, nwg%8==0.
template <bool BF16OUT>
__global__ __launch_bounds__(256) void gemm_nt_bf16(
    const bf16* __restrict__ A, const bf16* __restrict__ B,
    const float* __restrict__ bias, void* __restrict__ Cout,
    int K, int ldc, int Mstore, int Nstore, int nbx) {
  __shared__ char smem[65536];
  int t = threadIdx.x;
  int lane = t & 63, wave = t >> 6;
  int wm = wave >> 1, wn = wave & 1;
  int r16 = lane & 15, kg = lane >> 4;

  int nwg = gridDim.x;
  int cpx = nwg >> 3;
  int wg  = blockIdx.x;
  int swz = (wg & 7) * cpx + (wg >> 3);
  int bm0 = (swz % nbx) * 128;
  int bn0 = (swz / nbx) * 128;

  int rsub = lane >> 3;      // 0..7
  int cchk = lane & 7;       // 16B chunk within 128B row

  auto STAGE = [&](int buf, int k0) {
    char* Ab = smem + buf * 32768;
    char* Bb = Ab + 16384;
#pragma unroll
    for (int q = 0; q < 4; ++q) {
      int row = (wave * 4 + q) * 8 + rsub;
      int gc = cchk ^ (row & 7);
      gload16(&A[(size_t)(bm0 + row) * K + k0 + gc * 8], Ab + (wave * 4 + q) * 1024);
      gload16(&B[(size_t)(bn0 + row) * K + k0 + gc * 8], Bb + (wave * 4 + q) * 1024);
    }
  };

  f32x4 acc[4][4] = {};
  int rbA[4], rbB[4];
#pragma unroll
  for (int m = 0; m < 4; ++m) rbA[m] = (wm * 64 + m * 16 + r16) * 128;
#pragma unroll
  for (int n = 0; n < 4; ++n) rbB[n] = (wn * 64 + n * 16 + r16) * 128;
  int sw7 = r16 & 7;

  int nt = K >> 6;
  STAGE(0, 0);
  __syncthreads();
  for (int tt = 0; tt < nt; ++tt) {
    if (tt + 1 < nt) STAGE((tt & 1) ^ 1, (tt + 1) * 64);
    const char* Ab = smem + (tt & 1) * 32768;
    const char* Bb = Ab + 16384;
#pragma unroll
    for (int ks = 0; ks < 2; ++ks) {
      int ch = ((ks * 4 + kg) ^ sw7) * 16;
      bf16x8 af[4], bfr[4];
#pragma unroll
      for (int m = 0; m < 4; ++m)
        af[m] = *reinterpret_cast<const bf16x8*>(Ab + rbA[m] + ch);
#pragma unroll
      for (int n = 0; n < 4; ++n)
        bfr[n] = *reinterpret_cast<const bf16x8*>(Bb + rbB[n] + ch);
#pragma unroll
      for (int m = 0; m < 4; ++m)
#pragma unroll
        for (int n = 0; n < 4; ++n)
          acc[m][n] = __builtin_amdgcn_mfma_f32_16x16x32_bf16(af[m], bfr[n], acc[m][n], 0, 0, 0);
    }
    __syncthreads();
  }

  float bv[4];
#pragma unroll
  for (int n = 0; n < 4; ++n) {
    int gcol = bn0 + wn * 64 + n * 16 + r16;
    bv[n] = (gcol < Nstore) ? bias[gcol] : 0.f;
  }

  if constexpr (BF16OUT) {
    bf16* Cs = (bf16*)smem;
    bf16* Cg = (bf16*)Cout;
#pragma unroll
    for (int m = 0; m < 4; ++m) {
      int rb = wm * 64 + m * 16 + kg * 4;
#pragma unroll
      for (int n = 0; n < 4; ++n) {
        int cb = wn * 64 + n * 16 + r16;
#pragma unroll
        for (int r = 0; r < 4; ++r)
          Cs[(rb + r) * 128 + cb] = (bf16)(acc[m][n][r] + bv[n]);
      }
    }
    __syncthreads();
#pragma unroll
    for (int i = 0; i < 8; ++i) {
      int chunk = i * 256 + t;
      int row = chunk >> 4, c8 = chunk & 15;
      int grow = bm0 + row, gcol = bn0 + c8 * 8;
      if (grow < Mstore && gcol < Nstore)
        *reinterpret_cast<int4*>(&Cg[(size_t)grow * ldc + gcol]) =
            *reinterpret_cast<const int4*>(&Cs[row * 128 + c8 * 8]);
    }
  } else {
    float* Cs = (float*)smem;
    float* Cg = (float*)Cout;
#pragma unroll
    for (int m = 0; m < 4; ++m) {
      int rb = wm * 64 + m * 16 + kg * 4;
#pragma unroll
      for (int n = 0; n < 4; ++n) {
        int cb = wn * 64 + n * 16 + r16;
#pragma unroll
        for (int r = 0; r < 4; ++r)
          Cs[(rb + r) * 128 + cb] = acc[m][n][r] + bv[n];
      }
    }
    __syncthreads();
#pragma unroll
    for (int i = 0; i < 16; ++i) {
      int chunk = i * 256 + t;
      int row = chunk >> 5, cc = chunk & 31;
      int grow = bm0 + row, gcol = bn0 + cc * 4;
      if (grow < Mstore && gcol < Nstore) {
        f32x4 v = *reinterpret_cast<const f32x4*>(&Cs[row * 128 + cc * 4]);
        __builtin_nontemporal_store(v, reinterpret_cast<f32x4*>(&Cg[(size_t)grow * ldc + gcol]));
      }
    }
  }
}

// ---------------- GRU gates (h0 = 0, bf16 gi) -> h as bf16 ----------------
__global__ __launch_bounds__(256) void k_gru(const bf16* __restrict__ gi,
    const float* __restrict__ bhh, bf16* __restrict__ hb) {
  int i = blockIdx.x, g = threadIdx.x;
  float gr = (float)gi[(size_t)i * 768 + g]       + bhh[g];
  float gz = (float)gi[(size_t)i * 768 + 256 + g] + bhh[256 + g];
  float gn = (float)gi[(size_t)i * 768 + 512 + g];
  float r = 1.f / (1.f + expf(-gr));
  float z = 1.f / (1.f + expf(-gz));
  float n = tanhf(gn + r * bhh[512 + g]);
  hb[(size_t)i * GH + g] = (bf16)((1.f - z) * n);
}

extern "C" void kernel_launch(void* const* d_in, const int* in_sizes, int n_in,
                              void* d_out, int out_size, void* d_ws, size_t ws_size,
                              hipStream_t stream) {
  const float* x     = (const float*)d_in[0];
  const int*   ei    = (const int*)d_in[1];
  const float* Wl    = (const float*)d_in[2];
  const float* bl    = (const float*)d_in[3];
  const float* Wr    = (const float*)d_in[4];
  const float* br    = (const float*)d_in[5];
  const float* att   = (const float*)d_in[6];
  const float* gbias = (const float*)d_in[7];
  const float* Wih   = (const float*)d_in[8];
  // d_in[9] = W_hh: unused (h0 = 0)
  const float* bih   = (const float*)d_in[10];
  const float* bhh   = (const float*)d_in[11];
  const float* Wp    = (const float*)d_in[12];
  const float* bp    = (const float*)d_in[13];
  const float* lstd  = (const float*)d_in[14];
  float* out_mean = (float*)d_out;
  float* out_std  = out_mean + (size_t)N_NODES * N_NODES;

  char* w = (char*)d_ws;
  auto carve = [&](size_t bytes) {
    char* p = w; w += (bytes + 255) & ~(size_t)255; return p;
  };
  bf16*  xlb   = (bf16*)carve((size_t)N_NODES * HC * 2);
  bf16*  xrb   = (bf16*)carve((size_t)N_NODES * HC * 2);
  int*   src32 = (int*)carve((size_t)NE * 4);
  int*   dst32 = (int*)carve((size_t)NE * 4);
  int*   cnt   = (int*)carve((size_t)N_NODES * 4);
  int*   offs  = (int*)carve((size_t)(N_NODES + 1) * 4);
  int*   curs  = (int*)carve((size_t)N_NODES * 4);
  int*   csr_s = (int*)carve((size_t)NET * 4);
  int*   csr_d = (int*)carve((size_t)NET * 4);
  float* ex4   = (float*)carve((size_t)NET * 4 * 4);
  bf16*  gatb  = (bf16*)carve((size_t)MPAD * HC * 2);
  bf16*  wihb  = (bf16*)carve((size_t)768 * HC * 2);
  bf16*  gi    = (bf16*)carve((size_t)MPAD * 768 * 2);
  bf16*  hb    = (bf16*)carve((size_t)MPAD * GH * 2);
  bf16*  wpb   = (bf16*)carve((size_t)MPAD * GH * 2);

  k_lin<<<(N_NODES + 15) / 16, 256, 0, stream>>>(x, Wl, bl, Wr, br, xlb, xrb, lstd, out_std, cnt);
  k_decode_hist<<<(NET + 255) / 256, 256, 0, stream>>>(ei, src32, dst32, cnt, Wih, Wp, wihb, wpb);
  k_scan<<<1, 1024, 0, stream>>>(cnt, offs, curs);
  k_scatter<<<(NET + 255) / 256, 256, 0, stream>>>(src32, dst32, curs, csr_s, csr_d);
  k_edge<<<(NET + 15) / 16, 256, 0, stream>>>(xlb, xrb, csr_s, csr_d, att, ex4);
  k_agg<<<(N_NODES + 3) / 4, 256, 0, stream>>>(xlb, csr_s, offs, ex4, gbias, gatb);
  gemm_nt_bf16<true><<<40 * 6, 256, 0, stream>>>(gatb, wihb, bih, gi, 128, 768, N_NODES, 768, 40);
  k_gru<<<N_NODES, 256, 0, stream>>>(gi, bhh, hb);
  gemm_nt_bf16<false><<<40 * 40, 256, 0, stream>>>(hb, wpb, bp, out_mean, 256, N_NODES, N_NODES, N_NODES, 40);
}